// Round 5
// baseline (250.688 us; speedup 1.0000x reference)
//
#include <hip/hip_runtime.h>

#define I_DIM 28
#define H_DIM 64
#define T_DIM 128
#define B_DIM 4096
#define OUT_DIM 10
#define MB 16         // batch rows per block = full MFMA N
#define NTHREADS 256  // 4 waves; wave wv owns units 16wv..16wv+15, all 4 gates

typedef __attribute__((ext_vector_type(8))) short bf16x8;
typedef __attribute__((ext_vector_type(4))) float f32x4;
typedef __attribute__((ext_vector_type(4))) unsigned u32x4;

__device__ __forceinline__ unsigned f2bf_rne(float f) {
    unsigned u = __builtin_bit_cast(unsigned, f);
    return (u + 0x7FFFu + ((u >> 16) & 1u)) >> 16;
}
__device__ __forceinline__ float bfbits2f(unsigned b16) {
    return __builtin_bit_cast(float, b16 << 16);
}
__device__ __forceinline__ unsigned ftrunc_bf(float f) {
    return __builtin_bit_cast(unsigned, f) >> 16;
}

__device__ __forceinline__ void split_frag(const float* v, bf16x8& hi, bf16x8& lo) {
    unsigned hb[8], lb[8];
    #pragma unroll
    for (int j = 0; j < 8; ++j) {
        hb[j] = f2bf_rne(v[j]);
        float rem = v[j] - bfbits2f(hb[j]);
        lb[j] = ftrunc_bf(rem);
    }
    u32x4 hw, lw;
    #pragma unroll
    for (int i = 0; i < 4; ++i) {
        hw[i] = (hb[2*i+1] << 16) | (hb[2*i] & 0xFFFFu);
        lw[i] = (lb[2*i+1] << 16) | (lb[2*i] & 0xFFFFu);
    }
    hi = __builtin_bit_cast(bf16x8, hw);
    lo = __builtin_bit_cast(bf16x8, lw);
}

__device__ __forceinline__ float fast_rcp(float v) { return __builtin_amdgcn_rcpf(v); }
__device__ __forceinline__ float sigmoid_f(float v) { return fast_rcp(1.0f + __expf(-v)); }
__device__ __forceinline__ float tanh_f(float v) {
    float e = __expf(2.0f * v);
    return 1.0f - 2.0f * fast_rcp(e + 1.0f);
}

#define MFMA(A, B, C) __builtin_amdgcn_mfma_f32_16x16x32_bf16((A), (B), (C), 0, 0, 0)

__global__ __launch_bounds__(NTHREADS, 1)
void lstm_mfma_kernel(const float* __restrict__ x,
                      const float* __restrict__ W_ih,
                      const float* __restrict__ W_hh,
                      const float* __restrict__ b_ih,
                      const float* __restrict__ b_hh,
                      const float* __restrict__ W_out,
                      const float* __restrict__ b_out,
                      float* __restrict__ out)
{
    const int tid  = threadIdx.x;
    const int wv   = tid >> 6;        // wave 0..3 = unit-group
    const int lane = tid & 63;
    const int q    = lane >> 4;
    const int cm   = lane & 15;       // batch col n / A-row m
    const int b0   = blockIdx.x * MB;

    // h state, pre-split hi/lo, stored in exact B-frag order:
    // hfr[buf][kt][lane*4 + dw], dword dw = k-pair (8q_b+2dw, +1), lane = q_b*16 + n
    __shared__ __align__(16) unsigned hfr_hi[2][2][256];
    __shared__ __align__(16) unsigned hfr_lo[2][2][256];

    // ---- resident A-frags: wave wv, gate g -> rows g*64 + 16wv + cm
    bf16x8 Whh_hi[4][2], Whh_lo[4][2], Wih_hi[4], Wih_lo[4];
    f32x4  bias_c[4];
    #pragma unroll
    for (int g = 0; g < 4; ++g) {
        const int row = g * H_DIM + wv * 16 + cm;
        #pragma unroll
        for (int kt = 0; kt < 2; ++kt) {
            const float* wr = W_hh + row * H_DIM + kt * 32 + q * 8;
            float wt[8];
            float4 wa = *(const float4*)wr;
            float4 wb = *(const float4*)(wr + 4);
            wt[0]=wa.x; wt[1]=wa.y; wt[2]=wa.z; wt[3]=wa.w;
            wt[4]=wb.x; wt[5]=wb.y; wt[6]=wb.z; wt[7]=wb.w;
            split_frag(wt, Whh_hi[g][kt], Whh_lo[g][kt]);
        }
        {
            const float* ir = W_ih + row * I_DIM + q * 8;
            float wt[8];
            float4 ia = *(const float4*)ir;
            wt[0]=ia.x; wt[1]=ia.y; wt[2]=ia.z; wt[3]=ia.w;
            if (q < 3) {
                float4 ib = *(const float4*)(ir + 4);
                wt[4]=ib.x; wt[5]=ib.y; wt[6]=ib.z; wt[7]=ib.w;
            } else { wt[4]=0.f; wt[5]=0.f; wt[6]=0.f; wt[7]=0.f; }
            split_frag(wt, Wih_hi[g], Wih_lo[g]);
        }
        // C rows 4q+r -> unit 16wv+4q+r
        #pragma unroll
        for (int r = 0; r < 4; ++r) {
            const int brow = g * H_DIM + wv * 16 + 4 * q + r;
            bias_c[g][r] = b_ih[brow] + b_hh[brow];
        }
    }

    // zero h(0) buffer (buf 0)
    for (int i = tid; i < 512; i += NTHREADS) {
        (&hfr_hi[0][0][0])[i] = 0u;
        (&hfr_lo[0][0][0])[i] = 0u;
    }

    // ---- per-lane x loader: B-frag element x[b0+cm][t][8q+j]
    auto load_x = [&](int t, float4& xa, float4& xb) {
        const float* p = x + ((size_t)(b0 + cm) * T_DIM + t) * I_DIM + q * 8;
        xa = *(const float4*)p;
        if (q < 3) xb = *(const float4*)(p + 4);
        else       xb = float4{0.f, 0.f, 0.f, 0.f};
    };

    // prologue: xw for t=0
    f32x4 xw_t[4];
    {
        float4 xa, xb;
        load_x(0, xa, xb);
        float xt[8];
        xt[0]=xa.x; xt[1]=xa.y; xt[2]=xa.z; xt[3]=xa.w;
        xt[4]=xb.x; xt[5]=xb.y; xt[6]=xb.z; xt[7]=xb.w;
        bf16x8 Xhi, Xlo;
        split_frag(xt, Xhi, Xlo);
        #pragma unroll
        for (int g = 0; g < 4; ++g) {
            f32x4 a = MFMA(Wih_hi[g], Xhi, bias_c[g]);
            a = MFMA(Wih_lo[g], Xhi, a);
            a = MFMA(Wih_hi[g], Xlo, a);
            xw_t[g] = a;
        }
    }

    float c_st[4] = {0.f, 0.f, 0.f, 0.f};
    // h write position: unit u0 = 16wv+4q -> kt = wv>>1, qb = 2(wv&1)+(q>>1)
    const int ktw   = wv >> 1;
    const int lanep = (2 * (wv & 1) + (q >> 1)) * 16 + cm;
    const int dwoff = lanep * 4 + 2 * (q & 1);

    __syncthreads();   // h(0) zeros visible

    for (int t = 0; t < T_DIM; ++t) {
        const int rb = t & 1, wb = rb ^ 1;

        // issue x(t+1) loads first (latency hidden under MFMA phase)
        float4 xa_n, xb_n;
        load_x(t + 1 < T_DIM ? t + 1 : t, xa_n, xb_n);

        // h(t) B-frags (lane-consecutive b128, conflict-free)
        bf16x8 Hhi0 = __builtin_bit_cast(bf16x8, *(u32x4*)&hfr_hi[rb][0][lane * 4]);
        bf16x8 Hhi1 = __builtin_bit_cast(bf16x8, *(u32x4*)&hfr_hi[rb][1][lane * 4]);
        bf16x8 Hlo0 = __builtin_bit_cast(bf16x8, *(u32x4*)&hfr_lo[rb][0][lane * 4]);
        bf16x8 Hlo1 = __builtin_bit_cast(bf16x8, *(u32x4*)&hfr_lo[rb][1][lane * 4]);

        // recurrent GEMM: 4 independent chains of 6, C-init = xw(t) (bias folded)
        f32x4 acc[4];
        #pragma unroll
        for (int g = 0; g < 4; ++g) {
            f32x4 a = MFMA(Whh_hi[g][0], Hhi0, xw_t[g]);
            a = MFMA(Whh_hi[g][1], Hhi1, a);
            a = MFMA(Whh_lo[g][0], Hhi0, a);
            a = MFMA(Whh_lo[g][1], Hhi1, a);
            a = MFMA(Whh_hi[g][0], Hlo0, a);
            a = MFMA(Whh_hi[g][1], Hlo1, a);
            acc[g] = a;
        }

        // split x(t+1) and issue xw(t+1) MFMAs — overlaps the update below
        {
            float xt[8];
            xt[0]=xa_n.x; xt[1]=xa_n.y; xt[2]=xa_n.z; xt[3]=xa_n.w;
            xt[4]=xb_n.x; xt[5]=xb_n.y; xt[6]=xb_n.z; xt[7]=xb_n.w;
            bf16x8 Xhi, Xlo;
            split_frag(xt, Xhi, Xlo);
            #pragma unroll
            for (int g = 0; g < 4; ++g) {
                f32x4 a = MFMA(Wih_hi[g], Xhi, bias_c[g]);
                a = MFMA(Wih_lo[g], Xhi, a);
                a = MFMA(Wih_hi[g], Xlo, a);
                xw_t[g] = a;
            }
        }

        // in-register update of 4 cells (unit 16wv+4q+r, batch cm)
        float hv[4];
        #pragma unroll
        for (int r = 0; r < 4; ++r) {
            float ig = sigmoid_f(acc[0][r]);
            float fg = sigmoid_f(acc[1][r]);
            float gg = tanh_f  (acc[2][r]);
            float og = sigmoid_f(acc[3][r]);
            float cc = fg * c_st[r] + ig * gg;
            c_st[r] = cc;
            hv[r] = og * tanh_f(cc);
        }

        // split h, pack pairs (even k lo16, odd k hi16), write 2 dwords hi + 2 lo
        unsigned hb[4], lb[4];
        #pragma unroll
        for (int r = 0; r < 4; ++r) {
            hb[r] = f2bf_rne(hv[r]);
            lb[r] = ftrunc_bf(hv[r] - bfbits2f(hb[r]));
        }
        *(uint2*)&hfr_hi[wb][ktw][dwoff] =
            uint2{(hb[1] << 16) | (hb[0] & 0xFFFFu), (hb[3] << 16) | (hb[2] & 0xFFFFu)};
        *(uint2*)&hfr_lo[wb][ktw][dwoff] =
            uint2{(lb[1] << 16) | (lb[0] & 0xFFFFu), (lb[3] << 16) | (lb[2] & 0xFFFFu)};

        __syncthreads();   // h(t+1) visible for next step
    }

    // ---- output head: final h(T) is in buf 0 (T even)
    if (tid < MB * OUT_DIM) {
        const int bb = tid / OUT_DIM;
        const int o  = tid % OUT_DIM;
        float s = b_out[o];
        const float* wo = W_out + o * H_DIM;
        #pragma unroll
        for (int u = 0; u < H_DIM; ++u) {
            const int kt = u >> 5, kk = u & 31;
            const int dw = (kk >> 3) * 64 + bb * 4 + ((kk & 7) >> 1);
            const int sh = (u & 1) * 16;
            float h = bfbits2f((hfr_hi[0][kt][dw] >> sh) & 0xFFFFu)
                    + bfbits2f((hfr_lo[0][kt][dw] >> sh) & 0xFFFFu);
            s += h * wo[u];
        }
        out[(size_t)(b0 + bb) * OUT_DIM + o] = s;
    }
}

extern "C" void kernel_launch(void* const* d_in, const int* in_sizes, int n_in,
                              void* d_out, int out_size, void* d_ws, size_t ws_size,
                              hipStream_t stream) {
    const float* x     = (const float*)d_in[0];
    const float* W_ih  = (const float*)d_in[1];
    const float* W_hh  = (const float*)d_in[2];
    const float* b_ih  = (const float*)d_in[3];
    const float* b_hh  = (const float*)d_in[4];
    const float* W_out = (const float*)d_in[5];
    const float* b_out = (const float*)d_in[6];
    float* out = (float*)d_out;

    dim3 grid(B_DIM / MB);    // 256 blocks -> 1 per CU
    dim3 block(NTHREADS);     // 4 waves
    lstm_mfma_kernel<<<grid, block, 0, stream>>>(
        x, W_ih, W_hh, b_ih, b_hh, W_out, b_out, out);
}